// Round 1
// baseline (204.123 us; speedup 1.0000x reference)
//
#include <hip/hip_runtime.h>
#include <hip/hip_bf16.h>
#include <stdint.h>

#define B_DIM 8
#define C_DIM 512
#define N_DIM 3136
#define NP    3200   // N padded to 25*128
#define BK    32
#define NT    25     // NP/128

typedef short bf16x8 __attribute__((ext_vector_type(8)));
typedef float f32x4  __attribute__((ext_vector_type(4)));

__device__ __forceinline__ void gload16(const void* g, void* l) {
  __builtin_amdgcn_global_load_lds(
      (const __attribute__((address_space(1))) void*)g,
      (__attribute__((address_space(3))) void*)l, 16, 0, 0);
}

// x[b][c][n] f32 -> kt[b][n][c] bf16 (n padded to NP, pad rows zero)
__global__ __launch_bounds__(256) void k_transpose(const float* __restrict__ x,
                                                   ushort* __restrict__ kt) {
  __shared__ float tile[32][33];
  const int b  = blockIdx.z;
  const int n0 = blockIdx.x * 32;
  const int c0 = blockIdx.y * 32;
  const int tx = threadIdx.x;  // 32
  const int ty = threadIdx.y;  // 8
#pragma unroll
  for (int i = 0; i < 4; ++i) {
    int c = c0 + ty + 8 * i;
    int n = n0 + tx;
    float v = (n < N_DIM) ? x[((size_t)b * C_DIM + c) * N_DIM + n] : 0.0f;
    tile[ty + 8 * i][tx] = v;
  }
  __syncthreads();
#pragma unroll
  for (int i = 0; i < 4; ++i) {
    int n = n0 + ty + 8 * i;  // always < NP (grid covers NP exactly)
    float v = tile[tx][ty + 8 * i];
    __hip_bfloat16 h = __float2bfloat16(v);
    kt[((size_t)b * NP + n) * C_DIM + c0 + tx] = *(ushort*)&h;
  }
}

// rn[b][n] = 1/max(||x[b][:][n]||, 1e-8)  (fp32 exact); pad -> 0
__global__ __launch_bounds__(256) void k_norms(const float* __restrict__ x,
                                               float* __restrict__ rn) {
  const int b = blockIdx.y;
  const int n = blockIdx.x * 256 + threadIdx.x;
  if (n >= NP) return;
  if (n >= N_DIM) { rn[b * NP + n] = 0.0f; return; }
  const float* p = x + (size_t)b * C_DIM * N_DIM + n;
  float s = 0.0f;
#pragma unroll 4
  for (int c = 0; c < C_DIM; ++c) {
    float v = p[(size_t)c * N_DIM];
    s += v * v;
  }
  rn[b * NP + n] = 1.0f / fmaxf(sqrtf(s), 1e-8f);
}

// G = KT * KT^T per batch (both operands the same row-major [NP][C] bf16),
// epilogue scales by rn[row]*rn[col]. 128x128 tile, BK=32, 4 waves (2x2 of 64x64).
__global__ __launch_bounds__(256) void k_gemm(const ushort* __restrict__ kt,
                                              const float* __restrict__ rn,
                                              float* __restrict__ out) {
  __shared__ __attribute__((aligned(16))) ushort tA[128 * 32];
  __shared__ __attribute__((aligned(16))) ushort tB[128 * 32];
  const int b  = blockIdx.z;
  const int m0 = blockIdx.x * 128;  // cols
  const int n0 = blockIdx.y * 128;  // rows
  const int tid  = threadIdx.x;
  const int wave = tid >> 6;
  const int lane = tid & 63;
  const ushort* ktb = kt + (size_t)b * NP * C_DIM;

  const int wr = (wave >> 1) * 64;  // wave row offset in 128-tile
  const int wc = (wave & 1) * 64;   // wave col offset
  const int koff = lane >> 4;       // k-chunk 0..3 (8 bf16 each)
  const int rl = lane & 15;

  f32x4 acc[4][4];
#pragma unroll
  for (int mi = 0; mi < 4; ++mi)
#pragma unroll
    for (int ni = 0; ni < 4; ++ni)
      acc[mi][ni] = (f32x4){0.f, 0.f, 0.f, 0.f};

  for (int ks = 0; ks < C_DIM / BK; ++ks) {
    __syncthreads();
    // stage A(rows n0..n0+127) and B(rows m0..) tiles: 128x32 bf16 = 8KB each.
    // LDS is linear row-major [128][32]; the 16B chunk *within* a row is
    // swizzled: physical chunk p holds logical chunk p ^ ((row>>1)&3),
    // applied via the per-lane GLOBAL source address (rule #21).
    const int kbase = ks * BK;
#pragma unroll
    for (int i = 0; i < 2; ++i) {
      int q   = i * 256 + wave * 64 + lane;   // 16B chunk index 0..511
      int row = q >> 2;
      int lk  = (q & 3) ^ ((q >> 3) & 3);     // logical k-chunk for this slot
      const ushort* gA = ktb + (size_t)(n0 + row) * C_DIM + kbase + lk * 8;
      const ushort* gB = ktb + (size_t)(m0 + row) * C_DIM + kbase + lk * 8;
      char* lA = (char*)tA + (i * 256 + wave * 64) * 16;  // wave-uniform base
      char* lB = (char*)tB + (i * 256 + wave * 64) * 16;
      gload16(gA, lA);
      gload16(gB, lB);
    }
    __syncthreads();

    bf16x8 aF[4], bF[4];
#pragma unroll
    for (int mi = 0; mi < 4; ++mi) {
      int row  = wr + mi * 16 + rl;
      int phys = koff ^ ((row >> 1) & 3);
      aF[mi] = *(const bf16x8*)((const char*)tA + row * 64 + phys * 16);
    }
#pragma unroll
    for (int ni = 0; ni < 4; ++ni) {
      int row  = wc + ni * 16 + rl;
      int phys = koff ^ ((row >> 1) & 3);
      bF[ni] = *(const bf16x8*)((const char*)tB + row * 64 + phys * 16);
    }
#pragma unroll
    for (int mi = 0; mi < 4; ++mi)
#pragma unroll
      for (int ni = 0; ni < 4; ++ni)
        acc[mi][ni] = __builtin_amdgcn_mfma_f32_16x16x32_bf16(
            aF[mi], bF[ni], acc[mi][ni], 0, 0, 0);
  }

  // epilogue: out[row][col] = acc * rn[row] * rn[col]
  const float* rnb = rn + b * NP;
  float rrow[4][4], rcol[4];
#pragma unroll
  for (int mi = 0; mi < 4; ++mi)
#pragma unroll
    for (int r = 0; r < 4; ++r)
      rrow[mi][r] = rnb[n0 + wr + mi * 16 + koff * 4 + r];
#pragma unroll
  for (int ni = 0; ni < 4; ++ni)
    rcol[ni] = rnb[m0 + wc + ni * 16 + rl];

  float* outb = out + (size_t)b * N_DIM * N_DIM;
#pragma unroll
  for (int mi = 0; mi < 4; ++mi) {
#pragma unroll
    for (int ni = 0; ni < 4; ++ni) {
#pragma unroll
      for (int r = 0; r < 4; ++r) {
        int row = n0 + wr + mi * 16 + koff * 4 + r;
        int col = m0 + wc + ni * 16 + rl;
        if (row < N_DIM && col < N_DIM)
          outb[(size_t)row * N_DIM + col] =
              acc[mi][ni][r] * rrow[mi][r] * rcol[ni];
      }
    }
  }
}

extern "C" void kernel_launch(void* const* d_in, const int* in_sizes, int n_in,
                              void* d_out, int out_size, void* d_ws, size_t ws_size,
                              hipStream_t stream) {
  const float* x = (const float*)d_in[0];
  float* out = (float*)d_out;

  // workspace layout: KT bf16 [8][3200][512] then rn f32 [8][3200]
  ushort* kt = (ushort*)d_ws;
  float* rn = (float*)((char*)d_ws + (size_t)B_DIM * NP * C_DIM * 2);

  dim3 gT(NP / 32, C_DIM / 32, B_DIM);  // 100,16,8
  k_transpose<<<gT, dim3(32, 8), 0, stream>>>(x, kt);

  dim3 gN((NP + 255) / 256, B_DIM);     // 13,8
  k_norms<<<gN, 256, 0, stream>>>(x, rn);

  dim3 gG(NT, NT, B_DIM);               // 25,25,8
  k_gemm<<<gG, 256, 0, stream>>>(kt, rn, out);
}

// Round 2
// 134.630 us; speedup vs baseline: 1.5162x; 1.5162x over previous
//
#include <hip/hip_runtime.h>
#include <hip/hip_bf16.h>
#include <stdint.h>

#define B_DIM 8
#define C_DIM 512
#define N_DIM 3136
#define NP    3200   // N padded to 25*128
#define BK    32
#define NT    25     // NP/128
#define NTRI  (NT * (NT + 1) / 2)  // 325 lower-tri block tiles

typedef short bf16x8 __attribute__((ext_vector_type(8)));
typedef float f32x4  __attribute__((ext_vector_type(4)));

__device__ __forceinline__ void gload16(const void* g, void* l) {
  __builtin_amdgcn_global_load_lds(
      (const __attribute__((address_space(1))) void*)g,
      (__attribute__((address_space(3))) void*)l, 16, 0, 0);
}

__device__ __forceinline__ float bf2f(ushort u) {
  union { uint32_t i; float f; } c;
  c.i = ((uint32_t)u) << 16;
  return c.f;
}

// x[b][c][n] f32 -> kt[b][n][c] bf16 (n padded to NP, pad rows zero)
__global__ __launch_bounds__(256) void k_transpose(const float* __restrict__ x,
                                                   ushort* __restrict__ kt) {
  __shared__ float tile[32][33];
  const int b  = blockIdx.z;
  const int n0 = blockIdx.x * 32;
  const int c0 = blockIdx.y * 32;
  const int tx = threadIdx.x;  // 32
  const int ty = threadIdx.y;  // 8
#pragma unroll
  for (int i = 0; i < 4; ++i) {
    int c = c0 + ty + 8 * i;
    int n = n0 + tx;
    float v = (n < N_DIM) ? x[((size_t)b * C_DIM + c) * N_DIM + n] : 0.0f;
    tile[ty + 8 * i][tx] = v;
  }
  __syncthreads();
#pragma unroll
  for (int i = 0; i < 4; ++i) {
    int n = n0 + ty + 8 * i;
    float v = tile[tx][ty + 8 * i];
    __hip_bfloat16 h = __float2bfloat16(v);
    kt[((size_t)b * NP + n) * C_DIM + c0 + tx] = *(ushort*)&h;
  }
}

// sq[b*NP+n] = sum_c kt[b][n][c]^2 (fp32 accum over bf16 values).
// One wave per row; kt rows are contiguous -> b128 loads.
__global__ __launch_bounds__(256) void k_norms(const ushort* __restrict__ kt,
                                               float* __restrict__ sq) {
  const int row  = blockIdx.x * 4 + (threadIdx.x >> 6);  // 0..B*NP-1
  const int lane = threadIdx.x & 63;
  const ushort* p = kt + (size_t)row * C_DIM + lane * 8;
  bf16x8 v = *(const bf16x8*)p;
  float s = 0.0f;
#pragma unroll
  for (int j = 0; j < 8; ++j) {
    float f = bf2f((ushort)v[j]);
    s += f * f;
  }
#pragma unroll
  for (int m = 32; m >= 1; m >>= 1) s += __shfl_xor(s, m);
  if (lane == 0) sq[row] = s;
}

// Symmetric GEMM: only lower-tri block tiles (by <= bx). Direct write of the
// tile plus LDS-transposed mirror write, both coalesced. Epilogue normalizes
// by 1/max(||row||*||col||, eps) using sq[].
__global__ __launch_bounds__(256) void k_gemm(const ushort* __restrict__ kt,
                                              const float* __restrict__ sq,
                                              float* __restrict__ out) {
  // union: staging tiles (16 KB) during main loop; 64x132 f32 transpose
  // buffer (33 KB) during mirror epilogue.
  __shared__ __attribute__((aligned(16))) char smem[64 * 132 * 4];
  ushort* tA = (ushort*)smem;            // [128][32] bf16, 8 KB
  ushort* tB = (ushort*)(smem + 8192);   // [128][32] bf16, 8 KB
  float*  tr = (float*)smem;             // [64][132] f32, 33.8 KB

  const int b = blockIdx.z;
  // decode triangular index t -> (bx, by), by <= bx
  const int t = blockIdx.x;
  int bx = (int)((sqrtf(8.0f * (float)t + 1.0f) - 1.0f) * 0.5f);
  while ((bx + 1) * (bx + 2) / 2 <= t) ++bx;
  while (bx * (bx + 1) / 2 > t) --bx;
  const int by = t - bx * (bx + 1) / 2;

  const int n0 = bx * 128;  // rows (A tile)
  const int m0 = by * 128;  // cols (B tile)
  const int tid  = threadIdx.x;
  const int wave = tid >> 6;
  const int lane = tid & 63;
  const ushort* ktb = kt + (size_t)b * NP * C_DIM;

  const int wr = (wave >> 1) * 64;
  const int wc = (wave & 1) * 64;
  const int koff = lane >> 4;
  const int rl = lane & 15;

  f32x4 acc[4][4];
#pragma unroll
  for (int mi = 0; mi < 4; ++mi)
#pragma unroll
    for (int ni = 0; ni < 4; ++ni)
      acc[mi][ni] = (f32x4){0.f, 0.f, 0.f, 0.f};

  for (int ks = 0; ks < C_DIM / BK; ++ks) {
    __syncthreads();
    const int kbase = ks * BK;
#pragma unroll
    for (int i = 0; i < 2; ++i) {
      int q   = i * 256 + wave * 64 + lane;   // 16B chunk index 0..511
      int row = q >> 2;
      int lk  = (q & 3) ^ ((q >> 3) & 3);     // pre-swizzled global source
      const ushort* gA = ktb + (size_t)(n0 + row) * C_DIM + kbase + lk * 8;
      const ushort* gB = ktb + (size_t)(m0 + row) * C_DIM + kbase + lk * 8;
      char* lA = (char*)tA + (i * 256 + wave * 64) * 16;  // wave-uniform base
      char* lB = (char*)tB + (i * 256 + wave * 64) * 16;
      gload16(gA, lA);
      gload16(gB, lB);
    }
    __syncthreads();

    bf16x8 aF[4], bF[4];
#pragma unroll
    for (int mi = 0; mi < 4; ++mi) {
      int row  = wr + mi * 16 + rl;
      int phys = koff ^ ((row >> 1) & 3);
      aF[mi] = *(const bf16x8*)((const char*)tA + row * 64 + phys * 16);
    }
#pragma unroll
    for (int ni = 0; ni < 4; ++ni) {
      int row  = wc + ni * 16 + rl;
      int phys = koff ^ ((row >> 1) & 3);
      bF[ni] = *(const bf16x8*)((const char*)tB + row * 64 + phys * 16);
    }
#pragma unroll
    for (int mi = 0; mi < 4; ++mi)
#pragma unroll
      for (int ni = 0; ni < 4; ++ni)
        acc[mi][ni] = __builtin_amdgcn_mfma_f32_16x16x32_bf16(
            aF[mi], bF[ni], acc[mi][ni], 0, 0, 0);
  }

  // ---- epilogue ----
  const float* sqb = sq + b * NP;
  float rrow[4][4], rcol[4];
#pragma unroll
  for (int mi = 0; mi < 4; ++mi)
#pragma unroll
    for (int r = 0; r < 4; ++r) {
      float s = sqb[n0 + wr + mi * 16 + koff * 4 + r];
      rrow[mi][r] = 1.0f / fmaxf(sqrtf(s), 1e-8f);
    }
#pragma unroll
  for (int ni = 0; ni < 4; ++ni) {
    float s = sqb[m0 + wc + ni * 16 + rl];
    rcol[ni] = 1.0f / fmaxf(sqrtf(s), 1e-8f);
  }

  // scale acc in place: cosine values
#pragma unroll
  for (int mi = 0; mi < 4; ++mi)
#pragma unroll
    for (int ni = 0; ni < 4; ++ni)
#pragma unroll
      for (int r = 0; r < 4; ++r)
        acc[mi][ni][r] *= rrow[mi][r] * rcol[ni];

  float* outb = out + (size_t)b * N_DIM * N_DIM;

  // direct write: out[n0+row][m0+col]
#pragma unroll
  for (int mi = 0; mi < 4; ++mi) {
#pragma unroll
    for (int ni = 0; ni < 4; ++ni) {
#pragma unroll
      for (int r = 0; r < 4; ++r) {
        int row = n0 + wr + mi * 16 + koff * 4 + r;
        int col = m0 + wc + ni * 16 + rl;
        if (row < N_DIM && col < N_DIM)
          outb[(size_t)row * N_DIM + col] = acc[mi][ni][r];
      }
    }
  }

  // mirror write: out[m0+col][n0+row] via LDS transpose, two 64-col passes
  if (bx != by) {
#pragma unroll
    for (int h = 0; h < 2; ++h) {
      __syncthreads();  // protect tr vs prior readers (main loop / prev pass)
      if ((wave & 1) == h) {
        // this wave's cols are global m0 + h*64 + (ni*16+rl)
#pragma unroll
        for (int ni = 0; ni < 4; ++ni) {
          int colL = ni * 16 + rl;  // 0..63
#pragma unroll
          for (int mi = 0; mi < 4; ++mi) {
            int row = wr + mi * 16 + koff * 4;  // 16B-aligned
            *(f32x4*)(tr + colL * 132 + row) = acc[mi][ni];
          }
        }
      }
      __syncthreads();
      // all 256 threads stream out 64 rows x 128 cols, coalesced x4
#pragma unroll
      for (int it = 0; it < 8; ++it) {
        int i  = it * 8 + (tid >> 5);   // local mirror row 0..63
        int j4 = (tid & 31) * 4;        // col chunk
        int gm = m0 + h * 64 + i;       // global row (= original col)
        int gn = n0 + j4;               // global col (= original row)
        if (gm < N_DIM && gn < N_DIM) { // N_DIM % 4 == 0 -> chunk guard ok
          f32x4 v = *(const f32x4*)(tr + i * 132 + j4);
          *(f32x4*)(outb + (size_t)gm * N_DIM + gn) = v;
        }
      }
    }
  }
}

extern "C" void kernel_launch(void* const* d_in, const int* in_sizes, int n_in,
                              void* d_out, int out_size, void* d_ws, size_t ws_size,
                              hipStream_t stream) {
  const float* x = (const float*)d_in[0];
  float* out = (float*)d_out;

  // workspace: kt bf16 [8][3200][512], then sq f32 [8][3200]
  ushort* kt = (ushort*)d_ws;
  float* sq = (float*)((char*)d_ws + (size_t)B_DIM * NP * C_DIM * 2);

  dim3 gT(NP / 32, C_DIM / 32, B_DIM);  // 100,16,8
  k_transpose<<<gT, dim3(32, 8), 0, stream>>>(x, kt);

  k_norms<<<B_DIM * NP / 4, 256, 0, stream>>>(kt, sq);

  dim3 gG(NTRI, 1, B_DIM);              // 325,1,8
  k_gemm<<<gG, 256, 0, stream>>>(kt, sq, out);
}

// Round 3
// 133.498 us; speedup vs baseline: 1.5290x; 1.0085x over previous
//
#include <hip/hip_runtime.h>
#include <hip/hip_bf16.h>
#include <stdint.h>

#define B_DIM 8
#define C_DIM 512
#define N_DIM 3136
#define NP    3200   // N padded to 25*128
#define BK    32
#define NT    25     // NP/128
#define NTRI  (NT * (NT + 1) / 2)  // 325 lower-tri block tiles

typedef short bf16x8 __attribute__((ext_vector_type(8)));
typedef float f32x4  __attribute__((ext_vector_type(4)));

__device__ __forceinline__ void gload16(const void* g, void* l) {
  __builtin_amdgcn_global_load_lds(
      (const __attribute__((address_space(1))) void*)g,
      (__attribute__((address_space(3))) void*)l, 16, 0, 0);
}

__device__ __forceinline__ float bf2f(ushort u) {
  union { uint32_t i; float f; } c;
  c.i = ((uint32_t)u) << 16;
  return c.f;
}

__device__ __forceinline__ ushort f2bf(float f) {
  __hip_bfloat16 h = __float2bfloat16(f);
  return *(ushort*)&h;
}

// x[b][c][n] f32 -> kt[b][n][c] bf16 (n padded to NP, pad rows zero).
// 64c x 32n tiles; packed 2xbf16 uint stores -> full 128B segments.
__global__ __launch_bounds__(256) void k_transpose(const float* __restrict__ x,
                                                   ushort* __restrict__ kt) {
  __shared__ float tile[64][33];  // [c_local][n_local]
  const int b  = blockIdx.z;
  const int n0 = blockIdx.x * 32;
  const int c0 = blockIdx.y * 64;
  const int tx = threadIdx.x;  // 32 (n)
  const int ty = threadIdx.y;  // 8  (c)
#pragma unroll
  for (int j = 0; j < 8; ++j) {
    int c = c0 + ty + 8 * j;
    int n = n0 + tx;
    float v = (n < N_DIM) ? x[((size_t)b * C_DIM + c) * N_DIM + n] : 0.0f;
    tile[ty + 8 * j][tx] = v;
  }
  __syncthreads();
  const int tid = ty * 32 + tx;
  const int r = tid >> 5;   // n-sub 0..7
  const int p = tid & 31;   // c-pair 0..31
#pragma unroll
  for (int i = 0; i < 4; ++i) {
    int nl = r + 8 * i;
    int n = n0 + nl;
    uint32_t u = (uint32_t)f2bf(tile[2 * p][nl]) |
                 ((uint32_t)f2bf(tile[2 * p + 1][nl]) << 16);
    *(uint32_t*)(kt + ((size_t)b * NP + n) * C_DIM + c0 + 2 * p) = u;
  }
}

// sq[b*NP+n] = sum_c kt[b][n][c]^2 (fp32 accum over bf16 values).
__global__ __launch_bounds__(256) void k_norms(const ushort* __restrict__ kt,
                                               float* __restrict__ sq) {
  const int row  = blockIdx.x * 4 + (threadIdx.x >> 6);  // 0..B*NP-1
  const int lane = threadIdx.x & 63;
  const ushort* p = kt + (size_t)row * C_DIM + lane * 8;
  bf16x8 v = *(const bf16x8*)p;
  float s = 0.0f;
#pragma unroll
  for (int j = 0; j < 8; ++j) {
    float f = bf2f((ushort)v[j]);
    s += f * f;
  }
#pragma unroll
  for (int m = 32; m >= 1; m >>= 1) s += __shfl_xor(s, m);
  if (lane == 0) sq[row] = s;
}

// Symmetric GEMM, lower-tri block tiles, batch-pinned-to-XCD block mapping:
// blockIdx.x = t*8 + b  ->  XCD (= id%8) == batch  ->  per-XCD L2 working
// set is one batch's kt (3.2 MB < 4 MB L2).
__global__ __launch_bounds__(256) void k_gemm(const ushort* __restrict__ kt,
                                              const float* __restrict__ sq,
                                              float* __restrict__ out) {
  __shared__ __attribute__((aligned(16))) char smem[64 * 132 * 4];
  ushort* tA = (ushort*)smem;            // [128][32] bf16, 8 KB
  ushort* tB = (ushort*)(smem + 8192);   // [128][32] bf16, 8 KB
  float*  tr = (float*)smem;             // [64][132] f32 (epilogue union)

  const int id = blockIdx.x;
  const int b = id & 7;        // low 3 bits -> XCD round-robin
  const int t = id >> 3;       // triangular tile index 0..324
  int bx = (int)((sqrtf(8.0f * (float)t + 1.0f) - 1.0f) * 0.5f);
  while ((bx + 1) * (bx + 2) / 2 <= t) ++bx;
  while (bx * (bx + 1) / 2 > t) --bx;
  const int by = t - bx * (bx + 1) / 2;

  const int n0 = bx * 128;  // rows (A tile)
  const int m0 = by * 128;  // cols (B tile)
  const int tid  = threadIdx.x;
  const int wave = tid >> 6;
  const int lane = tid & 63;
  const ushort* ktb = kt + (size_t)b * NP * C_DIM;

  const int wr = (wave >> 1) * 64;
  const int wc = (wave & 1) * 64;
  const int koff = lane >> 4;
  const int rl = lane & 15;

  f32x4 acc[4][4];
#pragma unroll
  for (int mi = 0; mi < 4; ++mi)
#pragma unroll
    for (int ni = 0; ni < 4; ++ni)
      acc[mi][ni] = (f32x4){0.f, 0.f, 0.f, 0.f};

  for (int ks = 0; ks < C_DIM / BK; ++ks) {
    __syncthreads();
    const int kbase = ks * BK;
#pragma unroll
    for (int i = 0; i < 2; ++i) {
      int q   = i * 256 + wave * 64 + lane;   // 16B chunk index 0..511
      int row = q >> 2;
      int lk  = (q & 3) ^ ((q >> 3) & 3);     // pre-swizzled global source
      const ushort* gA = ktb + (size_t)(n0 + row) * C_DIM + kbase + lk * 8;
      const ushort* gB = ktb + (size_t)(m0 + row) * C_DIM + kbase + lk * 8;
      char* lA = (char*)tA + (i * 256 + wave * 64) * 16;  // wave-uniform base
      char* lB = (char*)tB + (i * 256 + wave * 64) * 16;
      gload16(gA, lA);
      gload16(gB, lB);
    }
    __syncthreads();

    bf16x8 aF[4], bF[4];
#pragma unroll
    for (int mi = 0; mi < 4; ++mi) {
      int row  = wr + mi * 16 + rl;
      int phys = koff ^ ((row >> 1) & 3);
      aF[mi] = *(const bf16x8*)((const char*)tA + row * 64 + phys * 16);
    }
#pragma unroll
    for (int ni = 0; ni < 4; ++ni) {
      int row  = wc + ni * 16 + rl;
      int phys = koff ^ ((row >> 1) & 3);
      bF[ni] = *(const bf16x8*)((const char*)tB + row * 64 + phys * 16);
    }
#pragma unroll
    for (int mi = 0; mi < 4; ++mi)
#pragma unroll
      for (int ni = 0; ni < 4; ++ni)
        acc[mi][ni] = __builtin_amdgcn_mfma_f32_16x16x32_bf16(
            aF[mi], bF[ni], acc[mi][ni], 0, 0, 0);
  }

  // ---- epilogue ----
  const float* sqb = sq + b * NP;
  float rrow[4][4], rcol[4];
#pragma unroll
  for (int mi = 0; mi < 4; ++mi)
#pragma unroll
    for (int r = 0; r < 4; ++r) {
      float s = sqb[n0 + wr + mi * 16 + koff * 4 + r];
      rrow[mi][r] = 1.0f / fmaxf(sqrtf(s), 1e-8f);
    }
#pragma unroll
  for (int ni = 0; ni < 4; ++ni) {
    float s = sqb[m0 + wc + ni * 16 + rl];
    rcol[ni] = 1.0f / fmaxf(sqrtf(s), 1e-8f);
  }

#pragma unroll
  for (int mi = 0; mi < 4; ++mi)
#pragma unroll
    for (int ni = 0; ni < 4; ++ni)
#pragma unroll
      for (int r = 0; r < 4; ++r)
        acc[mi][ni][r] *= rrow[mi][r] * rcol[ni];

  float* outb = out + (size_t)b * N_DIM * N_DIM;

  // direct write: out[n0+row][m0+col]
#pragma unroll
  for (int mi = 0; mi < 4; ++mi) {
#pragma unroll
    for (int ni = 0; ni < 4; ++ni) {
#pragma unroll
      for (int r = 0; r < 4; ++r) {
        int row = n0 + wr + mi * 16 + koff * 4 + r;
        int col = m0 + wc + ni * 16 + rl;
        if (row < N_DIM && col < N_DIM)
          outb[(size_t)row * N_DIM + col] = acc[mi][ni][r];
      }
    }
  }

  // mirror write: out[m0+col][n0+row] via LDS transpose, two 64-col passes
  if (bx != by) {
#pragma unroll
    for (int h = 0; h < 2; ++h) {
      __syncthreads();
      if ((wave & 1) == h) {
#pragma unroll
        for (int ni = 0; ni < 4; ++ni) {
          int colL = ni * 16 + rl;  // 0..63
#pragma unroll
          for (int mi = 0; mi < 4; ++mi) {
            int row = wr + mi * 16 + koff * 4;  // 16B-aligned
            *(f32x4*)(tr + colL * 132 + row) = acc[mi][ni];
          }
        }
      }
      __syncthreads();
#pragma unroll
      for (int it = 0; it < 8; ++it) {
        int i  = it * 8 + (tid >> 5);   // local mirror row 0..63
        int j4 = (tid & 31) * 4;        // col chunk
        int gm = m0 + h * 64 + i;       // global row (= original col)
        int gn = n0 + j4;               // global col (= original row)
        if (gm < N_DIM && gn < N_DIM) {
          f32x4 v = *(const f32x4*)(tr + i * 132 + j4);
          *(f32x4*)(outb + (size_t)gm * N_DIM + gn) = v;
        }
      }
    }
  }
}

extern "C" void kernel_launch(void* const* d_in, const int* in_sizes, int n_in,
                              void* d_out, int out_size, void* d_ws, size_t ws_size,
                              hipStream_t stream) {
  const float* x = (const float*)d_in[0];
  float* out = (float*)d_out;

  ushort* kt = (ushort*)d_ws;
  float* sq = (float*)((char*)d_ws + (size_t)B_DIM * NP * C_DIM * 2);

  dim3 gT(NP / 32, C_DIM / 64, B_DIM);  // 100,8,8
  k_transpose<<<gT, dim3(32, 8), 0, stream>>>(x, kt);

  k_norms<<<B_DIM * NP / 4, 256, 0, stream>>>(kt, sq);

  k_gemm<<<NTRI * B_DIM, 256, 0, stream>>>(kt, sq, out);  // 2600 blocks, b = id&7
}